// Round 8
// baseline (149.653 us; speedup 1.0000x reference)
//
#include <hip/hip_runtime.h>

#define NH 12

typedef __bf16 bf16x8 __attribute__((ext_vector_type(8)));
typedef __bf16 bf16x4 __attribute__((ext_vector_type(4)));
typedef float f32x4 __attribute__((ext_vector_type(4)));

typedef const __attribute__((address_space(1))) void* gas_ptr;
typedef __attribute__((address_space(3))) void* las_ptr;

__device__ __forceinline__ void gload_lds16(const __bf16* g, __bf16* l) {
    __builtin_amdgcn_global_load_lds((gas_ptr)g, (las_ptr)l, 16, 0, 0);
}

// Q scale folded with log2(e): attention runs in exp2 domain.
#define QSCALE 0.18033688011112042f   // 0.125 * log2(e)

// ---------------- fp32 -> bf16 conversion (vectorized: 8 elems/thread/iter) ----------------
__global__ void convert_kernel(const float* __restrict__ hs,
                               const float* __restrict__ w1,
                               const float* __restrict__ w2,
                               __bf16* __restrict__ xh,
                               __bf16* __restrict__ wq,
                               __bf16* __restrict__ wo) {
    const long long C0 = 786432;   // 6291456/8
    const long long C1 = 221184;   // 1769472/8
    const long long C2 = 73728;    // 589824/8
    long long i = (long long)blockIdx.x * blockDim.x + threadIdx.x;
    const long long stride = (long long)gridDim.x * blockDim.x;
    for (; i < C0 + C1 + C2; i += stride) {
        const float* src; __bf16* dst; long long j;
        if (i < C0)           { src = hs; dst = xh; j = i; }
        else if (i < C0 + C1) { src = w1; dst = wq; j = i - C0; }
        else                  { src = w2; dst = wo; j = i - C0 - C1; }
        f32x4 v0 = *(const f32x4*)(src + j * 8);
        f32x4 v1 = *(const f32x4*)(src + j * 8 + 4);
        bf16x8 o;
#pragma unroll
        for (int r = 0; r < 4; r++) { o[r] = (__bf16)v0[r]; o[4 + r] = (__bf16)v1[r]; }
        *(bf16x8*)(dst + j * 8) = o;
    }
}

// ---------------- NT bf16 MFMA GEMM, 8-phase schedule ----------------
// BM=256 x BN=128, BK=64. 512 threads / 8 waves (4M x 2N), wave tile 64x64.
// Per K-tile: 4 phases, each {ds_read subfrags || issue 2 stage-units ||
// s_barrier || (lgkm by compiler) || 8 MFMA || s_barrier}.
// NBUF=3 ring; stage tile t+2 during tile t (phases 0-2, 2 units each);
// vmcnt(6) once per K-tile (before its last barrier) retires tile t+1's
// 6 units, leaves tile t+2's 6 in flight ACROSS barriers. vmcnt(0) only
// at tile nT-2. XOR-swizzled LDS, bijective XCD swizzle.
template <int MODE>
__global__ __launch_bounds__(512) void gemm_nt(
    const __bf16* __restrict__ A, const __bf16* __restrict__ Bm,
    const float* __restrict__ bias,
    __bf16* __restrict__ qb, __bf16* __restrict__ kb, __bf16* __restrict__ vT,
    float* __restrict__ outf, int M, int N, int K, int NXB)
{
    __shared__ __bf16 As[3][256 * 64];   // 96 KB
    __shared__ __bf16 Bs[3][128 * 64];   // 48 KB
    const int t = threadIdx.x;
    const int lane = t & 63;
    const int w = t >> 6;
    const int wr = w >> 1, wc = w & 1;   // 4M x 2N wave grid
    const int fr = lane & 15, g4 = lane >> 4;

    const int cpx = gridDim.x >> 3;
    const int orig = blockIdx.x;
    const int swz = (orig & 7) * cpx + (orig >> 3);
    const int bx = swz % NXB, by = swz / NXB;
    const int m0 = by * 256, n0 = bx * 128;

    f32x4 acc[4][4];
    const f32x4 z4 = {0.f, 0.f, 0.f, 0.f};
#pragma unroll
    for (int i = 0; i < 4; i++)
#pragma unroll
        for (int j = 0; j < 4; j++) acc[i][j] = z4;

    const int nT = K >> 6;   // 12

    // stage units: A = 4 x 8KB (64 rows each), B = 2 x 8KB
    const __bf16* pA[4];  int lA[4];
    const __bf16* pB[2];  int lB[2];
#pragma unroll
    for (int u = 0; u < 4; u++) {
        const int c = u * 512 + t;
        const int row = c >> 3;
        const int cb = ((c & 7) ^ (row & 7)) * 8;   // pre-swizzled source chunk
        pA[u] = A + (size_t)(m0 + row) * K + cb;
        lA[u] = c * 8;
    }
#pragma unroll
    for (int u = 0; u < 2; u++) {
        const int c = u * 512 + t;
        const int row = c >> 3;
        const int cb = ((c & 7) ^ (row & 7)) * 8;
        pB[u] = Bm + (size_t)(n0 + row) * K + cb;
        lB[u] = c * 8;
    }

    // row indices for fragment reads (per wave)
    int rA[4], rB[4];
#pragma unroll
    for (int i = 0; i < 4; i++) rA[i] = wr * 64 + i * 16 + fr;
#pragma unroll
    for (int j = 0; j < 4; j++) rB[j] = wc * 64 + j * 16 + fr;

#define STA(q, u) { gload_lds16(pA[u], &As[q][lA[u]]); pA[u] += 64; }
#define STB(q, u) { gload_lds16(pB[u], &Bs[q][lB[u]]); pB[u] += 64; }
#define BAR()  { __builtin_amdgcn_s_barrier(); __builtin_amdgcn_sched_barrier(0); }

    // prologue: stage tiles 0 and 1 (12 units), wait tile 0 (keep 6 in flight)
    STA(0,0) STA(0,1) STA(0,2) STA(0,3) STB(0,0) STB(0,1)
    STA(1,0) STA(1,1) STA(1,2) STA(1,3) STB(1,0) STB(1,1)
    asm volatile("s_waitcnt vmcnt(6)" ::: "memory");
    BAR()

    for (int tI = 0; tI < nT; tI++) {
        const int p = tI % 3;
        const int q = (tI + 2) % 3;
        const bool pre = (tI + 2) < nT;
        bf16x8 af[4], bfr[2];

        // ---- phase 0: A kk0 + B cols0-1 kk0 | stage A-units 0,1 ----
#pragma unroll
        for (int i = 0; i < 4; i++)
            af[i] = *(const bf16x8*)&As[p][rA[i] * 64 + ((g4 ^ (rA[i] & 7)) * 8)];
#pragma unroll
        for (int j = 0; j < 2; j++)
            bfr[j] = *(const bf16x8*)&Bs[p][rB[j] * 64 + ((g4 ^ (rB[j] & 7)) * 8)];
        if (pre) { STA(q,0) STA(q,1) }
        BAR()
        __builtin_amdgcn_s_setprio(1);
#pragma unroll
        for (int i = 0; i < 4; i++)
#pragma unroll
            for (int j = 0; j < 2; j++)
                acc[i][j] = __builtin_amdgcn_mfma_f32_16x16x32_bf16(af[i], bfr[j], acc[i][j], 0, 0, 0);
        __builtin_amdgcn_s_setprio(0);
        BAR()

        // ---- phase 1: B cols2-3 kk0 | stage A-units 2,3 ----
#pragma unroll
        for (int j = 0; j < 2; j++)
            bfr[j] = *(const bf16x8*)&Bs[p][rB[2 + j] * 64 + ((g4 ^ (rB[2 + j] & 7)) * 8)];
        if (pre) { STA(q,2) STA(q,3) }
        BAR()
        __builtin_amdgcn_s_setprio(1);
#pragma unroll
        for (int i = 0; i < 4; i++)
#pragma unroll
            for (int j = 0; j < 2; j++)
                acc[i][2 + j] = __builtin_amdgcn_mfma_f32_16x16x32_bf16(af[i], bfr[j], acc[i][2 + j], 0, 0, 0);
        __builtin_amdgcn_s_setprio(0);
        BAR()

        // ---- phase 2: A kk1 + B cols0-1 kk1 | stage B-units 0,1 ----
#pragma unroll
        for (int i = 0; i < 4; i++)
            af[i] = *(const bf16x8*)&As[p][rA[i] * 64 + (((4 + g4) ^ (rA[i] & 7)) * 8)];
#pragma unroll
        for (int j = 0; j < 2; j++)
            bfr[j] = *(const bf16x8*)&Bs[p][rB[j] * 64 + (((4 + g4) ^ (rB[j] & 7)) * 8)];
        if (pre) { STB(q,0) STB(q,1) }
        BAR()
        __builtin_amdgcn_s_setprio(1);
#pragma unroll
        for (int i = 0; i < 4; i++)
#pragma unroll
            for (int j = 0; j < 2; j++)
                acc[i][j] = __builtin_amdgcn_mfma_f32_16x16x32_bf16(af[i], bfr[j], acc[i][j], 0, 0, 0);
        __builtin_amdgcn_s_setprio(0);
        BAR()

        // ---- phase 3: B cols2-3 kk1 | vmcnt once per K-tile ----
#pragma unroll
        for (int j = 0; j < 2; j++)
            bfr[j] = *(const bf16x8*)&Bs[p][rB[2 + j] * 64 + (((4 + g4) ^ (rB[2 + j] & 7)) * 8)];
        BAR()
        __builtin_amdgcn_s_setprio(1);
#pragma unroll
        for (int i = 0; i < 4; i++)
#pragma unroll
            for (int j = 0; j < 2; j++)
                acc[i][2 + j] = __builtin_amdgcn_mfma_f32_16x16x32_bf16(af[i], bfr[j], acc[i][2 + j], 0, 0, 0);
        __builtin_amdgcn_s_setprio(0);
        if (tI < nT - 2) {
            if (tI == nT - 3) asm volatile("s_waitcnt vmcnt(6)" ::: "memory");
            else if (tI < nT - 3) asm volatile("s_waitcnt vmcnt(6)" ::: "memory");
        } else if (tI == nT - 2) {
            asm volatile("s_waitcnt vmcnt(0)" ::: "memory");
        }
        if (tI < nT - 1) BAR()
    }
#undef STA
#undef STB
#undef BAR

#pragma unroll
    for (int j = 0; j < 4; j++) {
        const int gc = n0 + wc * 64 + j * 16 + fr;
        const float bv = bias[gc];
        int which = 0, head = 0, dim = 0;
        if (MODE == 0) {
            which = gc / 768;
            const int jj = gc - which * 768;
            head = jj >> 6; dim = jj & 63;
        }
#pragma unroll
        for (int i = 0; i < 4; i++)
#pragma unroll
            for (int r = 0; r < 4; r++) {
                const int gr = m0 + wr * 64 + i * 16 + g4 * 4 + r;
                const float val = acc[i][j][r] + bv;
                if (MODE == 0) {
                    const int s = gr >> 3, b = gr & 7;
                    const size_t n = (size_t)(b * NH + head);
                    if (which == 0)      qb[(n * 1024 + s) * 64 + dim] = (__bf16)(val * QSCALE);
                    else if (which == 1) kb[(n * 1024 + s) * 64 + dim] = (__bf16)val;
                    else                 vT[(n * 64 + dim) * 1024 + s] = (__bf16)val;
                } else {
                    outf[(size_t)gr * N + gc] = val;
                }
            }
    }
}

// ---------------- flash attention ----------------
__global__ __launch_bounds__(512) void attn_kernel(
    const __bf16* __restrict__ qb, const __bf16* __restrict__ kb,
    const __bf16* __restrict__ vT, __bf16* __restrict__ ctx)
{
    __shared__ __bf16 Kl[2][64 * 64];
    __shared__ __bf16 Vl[2][64 * 64];
    __shared__ __bf16 Pl[8][16 * 64];
    const int t = threadIdx.x, lane = t & 63, w = t >> 6;

    const int orig = blockIdx.x;
    const int swz = (orig & 7) * 96 + (orig >> 3);
    const int n = swz >> 3;
    const int q0 = (swz & 7) * 128;
    const int fr = lane & 15, g4 = lane >> 4;
    const int fx = fr & 7;

    const __bf16* qptr = qb + ((size_t)n * 1024 + q0 + w * 16 + fr) * 64 + g4 * 8;
    const bf16x8 qf0 = *(const bf16x8*)qptr;
    const bf16x8 qf1 = *(const bf16x8*)(qptr + 32);

    float mval = -1e30f, lval = 0.f;
    const f32x4 z4 = {0.f, 0.f, 0.f, 0.f};
    f32x4 o[4] = {z4, z4, z4, z4};

    const int srow = t >> 3;
    const int scb  = (t & 7) ^ (srow & 7);
    const __bf16* kbase = kb + (size_t)n * 65536;
    const __bf16* vbase = vT + (size_t)n * 65536;

    gload_lds16(kbase + (size_t)srow * 64 + scb * 8,   &Kl[0][t * 8]);
    gload_lds16(vbase + (size_t)srow * 1024 + scb * 8, &Vl[0][t * 8]);
    __syncthreads();

    int cur = 0;
    for (int kc = 0; kc < 16; kc++) {
        if (kc < 15) {
            const int t0 = (kc + 1) * 64;
            gload_lds16(kbase + (size_t)(t0 + srow) * 64 + scb * 8,  &Kl[cur ^ 1][t * 8]);
            gload_lds16(vbase + (size_t)srow * 1024 + t0 + scb * 8,  &Vl[cur ^ 1][t * 8]);
        }

        // ---- QK^T (swapped): sc[tt][r] = score[key = 16tt+4g4+r][q = fr] ----
        f32x4 sc[4];
        __builtin_amdgcn_s_setprio(1);
#pragma unroll
        for (int tt = 0; tt < 4; tt++) {
            const int row = (tt * 16 + fr) * 64;
            bf16x8 kf0 = *(const bf16x8*)&Kl[cur][row + ((g4 ^ fx) * 8)];
            bf16x8 kf1 = *(const bf16x8*)&Kl[cur][row + (((4 + g4) ^ fx) * 8)];
            f32x4 s = __builtin_amdgcn_mfma_f32_16x16x32_bf16(kf0, qf0, z4, 0, 0, 0);
            s = __builtin_amdgcn_mfma_f32_16x16x32_bf16(kf1, qf1, s, 0, 0, 0);
            sc[tt] = s;
        }
        __builtin_amdgcn_s_setprio(0);

        // ---- in-lane softmax over 16 values + cross-g4 (2 shfl) ----
        float a[16];
#pragma unroll
        for (int tt = 0; tt < 4; tt++)
#pragma unroll
            for (int r = 0; r < 4; r++) a[tt * 4 + r] = sc[tt][r];

        float m8[8];
#pragma unroll
        for (int i = 0; i < 8; i++) m8[i] = fmaxf(a[i], a[i + 8]);
        float m4a = fmaxf(m8[0], m8[4]), m4b = fmaxf(m8[1], m8[5]);
        float m4c = fmaxf(m8[2], m8[6]), m4d = fmaxf(m8[3], m8[7]);
        float pmax = fmaxf(fmaxf(m4a, m4b), fmaxf(m4c, m4d));
        pmax = fmaxf(pmax, __shfl_xor(pmax, 16));
        pmax = fmaxf(pmax, __shfl_xor(pmax, 32));

        if (pmax > mval + 8.0f) {
            const float sf = __builtin_amdgcn_exp2f(mval - pmax);
            lval *= sf;
#pragma unroll
            for (int dt = 0; dt < 4; dt++) o[dt] *= sf;
            mval = pmax;
        }

        float p[16];
#pragma unroll
        for (int i = 0; i < 16; i++) p[i] = __builtin_amdgcn_exp2f(a[i] - mval);
        float s8[8];
#pragma unroll
        for (int i = 0; i < 8; i++) s8[i] = p[i] + p[i + 8];
        float s4a = s8[0] + s8[4], s4b = s8[1] + s8[5];
        float s4c = s8[2] + s8[6], s4d = s8[3] + s8[7];
        float psum = (s4a + s4b) + (s4c + s4d);
        psum += __shfl_xor(psum, 16);
        psum += __shfl_xor(psum, 32);
        lval += psum;

#pragma unroll
        for (int tt = 0; tt < 4; tt++) {
            bf16x4 pk;
            pk[0] = (__bf16)p[tt * 4 + 0];
            pk[1] = (__bf16)p[tt * 4 + 1];
            pk[2] = (__bf16)p[tt * 4 + 2];
            pk[3] = (__bf16)p[tt * 4 + 3];
            const int blk = (2 * tt + (g4 >> 1)) ^ fx;
            *(bf16x4*)&Pl[w][fr * 64 + blk * 8 + (g4 & 1) * 4] = pk;
        }

        // ---- PV (swapped): o[dt][r] -> d = 16dt+4g4+r, q = fr ----
        __builtin_amdgcn_s_setprio(1);
#pragma unroll
        for (int ks = 0; ks < 2; ks++) {
            bf16x8 pa = *(const bf16x8*)&Pl[w][fr * 64 + (((4 * ks + g4) ^ fx) * 8)];
#pragma unroll
            for (int dt = 0; dt < 4; dt++) {
                bf16x8 vf = *(const bf16x8*)&Vl[cur][(dt * 16 + fr) * 64 + (((4 * ks + g4) ^ fx) * 8)];
                o[dt] = __builtin_amdgcn_mfma_f32_16x16x32_bf16(vf, pa, o[dt], 0, 0, 0);
            }
        }
        __builtin_amdgcn_s_setprio(0);

        if (kc < 15) __syncthreads();
        cur ^= 1;
    }

    const int b = n / NH, head = n % NH;
    const float rl = 1.0f / lval;
    const int srw = q0 + w * 16 + fr;
    __bf16* cbase = ctx + ((size_t)srw * 8 + b) * 768 + head * 64;
#pragma unroll
    for (int dt = 0; dt < 4; dt++) {
        bf16x4 ov;
#pragma unroll
        for (int r = 0; r < 4; r++) ov[r] = (__bf16)(o[dt][r] * rl);
        *(bf16x4*)&cbase[dt * 16 + g4 * 4] = ov;
    }
}

extern "C" void kernel_launch(void* const* d_in, const int* in_sizes, int n_in,
                              void* d_out, int out_size, void* d_ws, size_t ws_size,
                              hipStream_t stream) {
    const float* hs = (const float*)d_in[0];
    const float* w1 = (const float*)d_in[1];
    const float* b1 = (const float*)d_in[2];
    const float* w2 = (const float*)d_in[3];
    const float* b2 = (const float*)d_in[4];
    float* out = (float*)d_out;

    char* ws = (char*)d_ws;
    __bf16* qb  = (__bf16*)(ws);
    __bf16* kb  = (__bf16*)(ws + 12582912);
    __bf16* vT  = (__bf16*)(ws + 25165824);
    __bf16* Xh  = (__bf16*)(ws + 37748736);
    __bf16* Wq  = (__bf16*)(ws + 50331648);
    __bf16* Wo  = (__bf16*)(ws + 53870592);
    __bf16* Ctx = Xh;

    convert_kernel<<<2048, 256, 0, stream>>>(hs, w1, w2, Xh, Wq, Wo);
    gemm_nt<0><<<576, 512, 0, stream>>>(Xh, Wq, b1, qb, kb, vT, nullptr, 8192, 2304, 768, 18);
    attn_kernel<<<768, 512, 0, stream>>>(qb, kb, vT, Ctx);
    gemm_nt<1><<<192, 512, 0, stream>>>(Ctx, Wo, b2, nullptr, nullptr, nullptr, out, 8192, 768, 768, 6);
}

// Round 9
// 116.949 us; speedup vs baseline: 1.2797x; 1.2797x over previous
//
#include <hip/hip_runtime.h>

#define NH 12

typedef __bf16 bf16x8 __attribute__((ext_vector_type(8)));
typedef __bf16 bf16x4 __attribute__((ext_vector_type(4)));
typedef float f32x4 __attribute__((ext_vector_type(4)));

typedef const __attribute__((address_space(1))) void* gas_ptr;
typedef __attribute__((address_space(3))) void* las_ptr;

__device__ __forceinline__ void gload_lds16(const __bf16* g, __bf16* l) {
    __builtin_amdgcn_global_load_lds((gas_ptr)g, (las_ptr)l, 16, 0, 0);
}

// Q scale folded with log2(e): attention runs in exp2 domain.
#define QSCALE 0.18033688011112042f   // 0.125 * log2(e)

// ---------------- fp32 -> bf16 conversion (vectorized: 8 elems/thread/iter) ----------------
__global__ void convert_kernel(const float* __restrict__ hs,
                               const float* __restrict__ w1,
                               const float* __restrict__ w2,
                               __bf16* __restrict__ xh,
                               __bf16* __restrict__ wq,
                               __bf16* __restrict__ wo) {
    const long long C0 = 786432;   // 6291456/8
    const long long C1 = 221184;   // 1769472/8
    const long long C2 = 73728;    // 589824/8
    long long i = (long long)blockIdx.x * blockDim.x + threadIdx.x;
    const long long stride = (long long)gridDim.x * blockDim.x;
    for (; i < C0 + C1 + C2; i += stride) {
        const float* src; __bf16* dst; long long j;
        if (i < C0)           { src = hs; dst = xh; j = i; }
        else if (i < C0 + C1) { src = w1; dst = wq; j = i - C0; }
        else                  { src = w2; dst = wo; j = i - C0 - C1; }
        f32x4 v0 = *(const f32x4*)(src + j * 8);
        f32x4 v1 = *(const f32x4*)(src + j * 8 + 4);
        bf16x8 o;
#pragma unroll
        for (int r = 0; r < 4; r++) { o[r] = (__bf16)v0[r]; o[4 + r] = (__bf16)v1[r]; }
        *(bf16x8*)(dst + j * 8) = o;
    }
}

// ---------------- NT bf16 MFMA GEMM: C = A(MxK) * B(NxK)^T + bias ----------------
// BM x 128 tile (BM=128: 512 thr / 8 waves 2x4; BM=64: 256 thr / 4 waves 1x4),
// BK=64, NBUF=2 double-buffer (1 __syncthreads per K-step), XOR-swizzled LDS,
// bijective XCD swizzle. MODE 0: vT blocks route through an LDS-staged
// epilogue (padded [128][130] f32 tile) for coalesced 32B stores; q/k blocks
// store direct (already 32B-contiguous per fr-group). MODE 1: fp32 direct.
template <int MODE, int BM>
__global__ __launch_bounds__(BM * 4) void gemm_nt(
    const __bf16* __restrict__ A, const __bf16* __restrict__ Bm,
    const float* __restrict__ bias,
    __bf16* __restrict__ qb, __bf16* __restrict__ kb, __bf16* __restrict__ vT,
    float* __restrict__ outf, int M, int N, int K, int NXB)
{
    constexpr int THREADS = BM * 4;
    constexpr int ASZ = BM * 64 * 2;        // bytes per A buffer
    constexpr int BSZ = 128 * 64 * 2;       // bytes per B buffer
    constexpr int BUNITS = 1024 / THREADS;  // B stage units per thread
    constexpr int SMEMSZ = (MODE == 0) ? 66560 : (2 * ASZ + 2 * BSZ);
    __shared__ __align__(16) char SMEM[SMEMSZ];

    const int t = threadIdx.x;
    const int lane = t & 63;
    const int w = t >> 6;
    const int wr = w >> 2, wc = w & 3;      // wave tile 64x32
    const int fr = lane & 15, g4 = lane >> 4;

    const int cpx = gridDim.x >> 3;
    const int orig = blockIdx.x;
    const int swz = (orig & 7) * cpx + (orig >> 3);
    const int bx = swz % NXB, by = swz / NXB;
    const int m0 = by * BM, n0 = bx * 128;

    f32x4 acc[4][2];
    const f32x4 z4 = {0.f, 0.f, 0.f, 0.f};
#pragma unroll
    for (int i = 0; i < 4; i++)
#pragma unroll
        for (int j = 0; j < 2; j++) acc[i][j] = z4;

    const int kSteps = K >> 6;

    auto As_ = [&](int b) { return (__bf16*)(SMEM + b * ASZ); };
    auto Bs_ = [&](int b) { return (__bf16*)(SMEM + 2 * ASZ + b * BSZ); };

    auto stage = [&](int tk, int b) {
#pragma unroll
        for (int u = 0; u < 2; u++) {
            const int c = u * THREADS + t;
            const int row = c >> 3;
            const int cb = ((c & 7) ^ (row & 7)) * 8;   // pre-swizzled source
            gload_lds16(A + (size_t)(m0 + row) * K + tk * 64 + cb, As_(b) + c * 8);
        }
#pragma unroll
        for (int u = 0; u < BUNITS; u++) {
            const int c = u * THREADS + t;
            const int row = c >> 3;
            const int cb = ((c & 7) ^ (row & 7)) * 8;
            gload_lds16(Bm + (size_t)(n0 + row) * K + tk * 64 + cb, Bs_(b) + c * 8);
        }
    };

    auto compute = [&](int cur) {
#pragma unroll
        for (int h = 0; h < 2; h++) {
            bf16x8 af[4], bfr[2];
#pragma unroll
            for (int i = 0; i < 4; i++) {
                const int r = wr * 64 + i * 16 + fr;
                af[i] = *(const bf16x8*)&As_(cur)[r * 64 + (((h * 4 + g4) ^ (r & 7)) * 8)];
            }
#pragma unroll
            for (int j = 0; j < 2; j++) {
                const int r = wc * 32 + j * 16 + fr;
                bfr[j] = *(const bf16x8*)&Bs_(cur)[r * 64 + (((h * 4 + g4) ^ (r & 7)) * 8)];
            }
            __builtin_amdgcn_s_setprio(1);
#pragma unroll
            for (int i = 0; i < 4; i++)
#pragma unroll
                for (int j = 0; j < 2; j++)
                    acc[i][j] = __builtin_amdgcn_mfma_f32_16x16x32_bf16(af[i], bfr[j], acc[i][j], 0, 0, 0);
            __builtin_amdgcn_s_setprio(0);
        }
    };

    stage(0, 0);
    __syncthreads();
    int cur = 0;
    for (int ks = 0; ks < kSteps; ks++) {
        if (ks < kSteps - 1) stage(ks + 1, cur ^ 1);
        compute(cur);
        __syncthreads();
        cur ^= 1;
    }

    if constexpr (MODE == 1) {
#pragma unroll
        for (int j = 0; j < 2; j++) {
            const int gc = n0 + wc * 32 + j * 16 + fr;
            const float bv = bias[gc];
#pragma unroll
            for (int i = 0; i < 4; i++)
#pragma unroll
                for (int r = 0; r < 4; r++) {
                    const int gr = m0 + wr * 64 + i * 16 + g4 * 4 + r;
                    outf[(size_t)gr * N + gc] = acc[i][j][r] + bv;
                }
        }
    } else {
        const int which = (n0 >= 1536) ? 2 : (n0 >= 768 ? 1 : 0);
        if (which < 2) {
            // q/k: direct stores (fr-group writes 32B contiguous)
#pragma unroll
            for (int j = 0; j < 2; j++) {
                const int gc = n0 + wc * 32 + j * 16 + fr;
                const float bv = bias[gc];
                const int jj = gc - which * 768;
                const int head = jj >> 6, dim = jj & 63;
#pragma unroll
                for (int i = 0; i < 4; i++)
#pragma unroll
                    for (int r = 0; r < 4; r++) {
                        const int gr = m0 + wr * 64 + i * 16 + g4 * 4 + r;
                        const int s = gr >> 3, b = gr & 7;
                        const size_t n = (size_t)(b * NH + head);
                        const float val = acc[i][j][r] + bv;
                        if (which == 0) qb[(n * 1024 + s) * 64 + dim] = (__bf16)(val * QSCALE);
                        else            kb[(n * 1024 + s) * 64 + dim] = (__bf16)val;
                    }
            }
        } else {
            // vT: stage C-tile in LDS (padded 130 f32/row, conflict-free),
            // re-read dim-major, store 16 s-values (32B) contiguous per chunk.
            float* Cw = (float*)SMEM;
#pragma unroll
            for (int j = 0; j < 2; j++) {
                const int col = wc * 32 + j * 16 + fr;
                const float bv = bias[n0 + col];
#pragma unroll
                for (int i = 0; i < 4; i++)
#pragma unroll
                    for (int r = 0; r < 4; r++) {
                        const int l = wr * 64 + i * 16 + g4 * 4 + r;
                        Cw[l * 130 + col] = acc[i][j][r] + bv;
                    }
            }
            __syncthreads();
            const int hbase = (n0 - 1536) >> 6;
            const int s0 = m0 >> 3;
#pragma unroll
            for (int u = 0; u < 2; u++) {
                const int c = u * THREADS + t;       // 0..1023
                const int b = c >> 7;                // batch 0..7
                const int hd = (c >> 6) & 1;         // head-in-tile
                const int dim = c & 63;
                const size_t n = (size_t)(b * NH + hbase + hd);
                __bf16* dst = vT + (n * 64 + dim) * 1024 + s0;
                bf16x8 o0, o1;
#pragma unroll
                for (int sl = 0; sl < 8; sl++)
                    o0[sl] = (__bf16)Cw[(sl * 8 + b) * 130 + hd * 64 + dim];
#pragma unroll
                for (int sl = 0; sl < 8; sl++)
                    o1[sl] = (__bf16)Cw[((sl + 8) * 8 + b) * 130 + hd * 64 + dim];
                *(bf16x8*)dst = o0;
                *(bf16x8*)(dst + 8) = o1;
            }
        }
    }
}

// ---------------- flash attention ----------------
__global__ __launch_bounds__(512) void attn_kernel(
    const __bf16* __restrict__ qb, const __bf16* __restrict__ kb,
    const __bf16* __restrict__ vT, __bf16* __restrict__ ctx)
{
    __shared__ __bf16 Kl[2][64 * 64];
    __shared__ __bf16 Vl[2][64 * 64];
    __shared__ __bf16 Pl[8][16 * 64];
    const int t = threadIdx.x, lane = t & 63, w = t >> 6;

    const int orig = blockIdx.x;
    const int swz = (orig & 7) * 96 + (orig >> 3);
    const int n = swz >> 3;
    const int q0 = (swz & 7) * 128;
    const int fr = lane & 15, g4 = lane >> 4;
    const int fx = fr & 7;

    const __bf16* qptr = qb + ((size_t)n * 1024 + q0 + w * 16 + fr) * 64 + g4 * 8;
    const bf16x8 qf0 = *(const bf16x8*)qptr;
    const bf16x8 qf1 = *(const bf16x8*)(qptr + 32);

    float mval = -1e30f, lval = 0.f;
    const f32x4 z4 = {0.f, 0.f, 0.f, 0.f};
    f32x4 o[4] = {z4, z4, z4, z4};

    const int srow = t >> 3;
    const int scb  = (t & 7) ^ (srow & 7);
    const __bf16* kbase = kb + (size_t)n * 65536;
    const __bf16* vbase = vT + (size_t)n * 65536;

    gload_lds16(kbase + (size_t)srow * 64 + scb * 8,   &Kl[0][t * 8]);
    gload_lds16(vbase + (size_t)srow * 1024 + scb * 8, &Vl[0][t * 8]);
    __syncthreads();

    int cur = 0;
    for (int kc = 0; kc < 16; kc++) {
        if (kc < 15) {
            const int t0 = (kc + 1) * 64;
            gload_lds16(kbase + (size_t)(t0 + srow) * 64 + scb * 8,  &Kl[cur ^ 1][t * 8]);
            gload_lds16(vbase + (size_t)srow * 1024 + t0 + scb * 8,  &Vl[cur ^ 1][t * 8]);
        }

        // ---- QK^T (swapped): sc[tt][r] = score[key = 16tt+4g4+r][q = fr] ----
        f32x4 sc[4];
        __builtin_amdgcn_s_setprio(1);
#pragma unroll
        for (int tt = 0; tt < 4; tt++) {
            const int row = (tt * 16 + fr) * 64;
            bf16x8 kf0 = *(const bf16x8*)&Kl[cur][row + ((g4 ^ fx) * 8)];
            bf16x8 kf1 = *(const bf16x8*)&Kl[cur][row + (((4 + g4) ^ fx) * 8)];
            f32x4 s = __builtin_amdgcn_mfma_f32_16x16x32_bf16(kf0, qf0, z4, 0, 0, 0);
            s = __builtin_amdgcn_mfma_f32_16x16x32_bf16(kf1, qf1, s, 0, 0, 0);
            sc[tt] = s;
        }
        __builtin_amdgcn_s_setprio(0);

        // ---- in-lane softmax over 16 values + cross-g4 (2 shfl) ----
        float a[16];
#pragma unroll
        for (int tt = 0; tt < 4; tt++)
#pragma unroll
            for (int r = 0; r < 4; r++) a[tt * 4 + r] = sc[tt][r];

        float m8[8];
#pragma unroll
        for (int i = 0; i < 8; i++) m8[i] = fmaxf(a[i], a[i + 8]);
        float m4a = fmaxf(m8[0], m8[4]), m4b = fmaxf(m8[1], m8[5]);
        float m4c = fmaxf(m8[2], m8[6]), m4d = fmaxf(m8[3], m8[7]);
        float pmax = fmaxf(fmaxf(m4a, m4b), fmaxf(m4c, m4d));
        pmax = fmaxf(pmax, __shfl_xor(pmax, 16));
        pmax = fmaxf(pmax, __shfl_xor(pmax, 32));

        if (pmax > mval + 8.0f) {
            const float sf = __builtin_amdgcn_exp2f(mval - pmax);
            lval *= sf;
#pragma unroll
            for (int dt = 0; dt < 4; dt++) o[dt] *= sf;
            mval = pmax;
        }

        float p[16];
#pragma unroll
        for (int i = 0; i < 16; i++) p[i] = __builtin_amdgcn_exp2f(a[i] - mval);
        float s8[8];
#pragma unroll
        for (int i = 0; i < 8; i++) s8[i] = p[i] + p[i + 8];
        float s4a = s8[0] + s8[4], s4b = s8[1] + s8[5];
        float s4c = s8[2] + s8[6], s4d = s8[3] + s8[7];
        float psum = (s4a + s4b) + (s4c + s4d);
        psum += __shfl_xor(psum, 16);
        psum += __shfl_xor(psum, 32);
        lval += psum;

#pragma unroll
        for (int tt = 0; tt < 4; tt++) {
            bf16x4 pk;
            pk[0] = (__bf16)p[tt * 4 + 0];
            pk[1] = (__bf16)p[tt * 4 + 1];
            pk[2] = (__bf16)p[tt * 4 + 2];
            pk[3] = (__bf16)p[tt * 4 + 3];
            const int blk = (2 * tt + (g4 >> 1)) ^ fx;
            *(bf16x4*)&Pl[w][fr * 64 + blk * 8 + (g4 & 1) * 4] = pk;
        }

        // ---- PV (swapped): o[dt][r] -> d = 16dt+4g4+r, q = fr ----
        __builtin_amdgcn_s_setprio(1);
#pragma unroll
        for (int ks = 0; ks < 2; ks++) {
            bf16x8 pa = *(const bf16x8*)&Pl[w][fr * 64 + (((4 * ks + g4) ^ fx) * 8)];
#pragma unroll
            for (int dt = 0; dt < 4; dt++) {
                bf16x8 vf = *(const bf16x8*)&Vl[cur][(dt * 16 + fr) * 64 + (((4 * ks + g4) ^ fx) * 8)];
                o[dt] = __builtin_amdgcn_mfma_f32_16x16x32_bf16(vf, pa, o[dt], 0, 0, 0);
            }
        }
        __builtin_amdgcn_s_setprio(0);

        if (kc < 15) __syncthreads();
        cur ^= 1;
    }

    const int b = n / NH, head = n % NH;
    const float rl = 1.0f / lval;
    const int srw = q0 + w * 16 + fr;
    __bf16* cbase = ctx + ((size_t)srw * 8 + b) * 768 + head * 64;
#pragma unroll
    for (int dt = 0; dt < 4; dt++) {
        bf16x4 ov;
#pragma unroll
        for (int r = 0; r < 4; r++) ov[r] = (__bf16)(o[dt][r] * rl);
        *(bf16x4*)&cbase[dt * 16 + g4 * 4] = ov;
    }
}

extern "C" void kernel_launch(void* const* d_in, const int* in_sizes, int n_in,
                              void* d_out, int out_size, void* d_ws, size_t ws_size,
                              hipStream_t stream) {
    const float* hs = (const float*)d_in[0];
    const float* w1 = (const float*)d_in[1];
    const float* b1 = (const float*)d_in[2];
    const float* w2 = (const float*)d_in[3];
    const float* b2 = (const float*)d_in[4];
    float* out = (float*)d_out;

    char* ws = (char*)d_ws;
    __bf16* qb  = (__bf16*)(ws);
    __bf16* kb  = (__bf16*)(ws + 12582912);
    __bf16* vT  = (__bf16*)(ws + 25165824);
    __bf16* Xh  = (__bf16*)(ws + 37748736);
    __bf16* Wq  = (__bf16*)(ws + 50331648);
    __bf16* Wo  = (__bf16*)(ws + 53870592);
    __bf16* Ctx = Xh;

    convert_kernel<<<2048, 256, 0, stream>>>(hs, w1, w2, Xh, Wq, Wo);
    gemm_nt<0, 128><<<1152, 512, 0, stream>>>(Xh, Wq, b1, qb, kb, vT, nullptr, 8192, 2304, 768, 18);
    attn_kernel<<<768, 512, 0, stream>>>(qb, kb, vT, Ctx);
    gemm_nt<1, 64><<<768, 256, 0, stream>>>(Ctx, Wo, b2, nullptr, nullptr, nullptr, out, 8192, 768, 768, 6);
}